// Round 1
// baseline (96.002 us; speedup 1.0000x reference)
//
#include <hip/hip_runtime.h>
#include <stdint.h>

#define DIM   128
#define MN    1024
#define BATCH 2048
#define ALPHA 0.3f
#define SIGMA 16.0f
#define LOG2E 1.44269504088896f

typedef _Float16 half8 __attribute__((ext_vector_type(8)));
typedef float    floatx4 __attribute__((ext_vector_type(4)));

// ws layout (float units):
//   S[128][1024]  @ 0        binned sums, SoA by dim (524288 B)
//   cnt[1024]     @ 131072   bin counts (4096 B)
//   flags[128]    @ 132096   pair-combine flags, u32 (512 B)
//   keys[2][2048] @ 132224   partial argmin keys, u64 (32 KB)
// First three regions zeroed each iteration by a hipMemsetAsync graph node.
#define S_OFF    0
#define CNT_OFF  (128 * 1024)
#define FLAG_OFF (CNT_OFF + 1024)
#define KEY_OFF  (FLAG_OFF + 128)
#define MEMSET_BYTES (KEY_OFF * 4)

// ---------------------------------------------------------------------------
// Kernel 1: BMU + pair-combine + global binning.
// 256 blocks x 1024 thr (16 waves, 4/SIMD) — full chip.
// Block = (batch-group bg = bid>>1 : 16 batches, half h = bid&1 : 512 units).
// Phase A (unchanged): hi/lo f16 3-product MFMA distances, in-block argmin,
// partial key per batch stored agent-scope.
// Phase B (new): the SECOND block of each (bg) pair — decided by an agent
// acq_rel fetch_add on flags[bg], no spinning — loads the partner's 16 keys
// (agent loads; release chain: relaxed agent stores -> __syncthreads (drains
// vmcnt) -> acq_rel RMW), min-combines (unit in low bits keeps first-index
// tie-break), then bins x[b] into global S/cnt with device-scope f32 atomics.
// Binning thus happens ONCE, not 8x per uxg block as before.
// ---------------------------------------------------------------------------
__global__ __launch_bounds__(1024) void bmu_bin_kernel(
    const float* __restrict__ x, const float* __restrict__ w,
    float* __restrict__ ws)
{
  __shared__ unsigned long long kb[16][16];
  __shared__ unsigned int vcell[16];
  __shared__ int oldflag;

  float* S   = ws + S_OFF;
  float* cnt = ws + CNT_OFF;
  unsigned int* flags = (unsigned int*)(ws + FLAG_OFF);
  unsigned long long* keys = (unsigned long long*)(ws + KEY_OFF);

  const int t    = threadIdx.x;
  const int lane = t & 63;
  const int wv   = t >> 6;            // 16 waves
  const int bg   = blockIdx.x >> 1;
  const int b0   = bg * 16;
  const int h    = blockIdx.x & 1;
  const int r    = lane & 15;
  const int q    = lane >> 4;

  // B-frags from x, in-register hi/lo split
  half8 Bh[4], Bl[4];
  {
    const float* xr = x + (b0 + r) * DIM + q * 8;
#pragma unroll
    for (int c = 0; c < 4; ++c) {
      float4 v0 = *reinterpret_cast<const float4*>(xr + c * 32);
      float4 v1 = *reinterpret_cast<const float4*>(xr + c * 32 + 4);
      float xs[8] = {v0.x, v0.y, v0.z, v0.w, v1.x, v1.y, v1.z, v1.w};
#pragma unroll
      for (int j = 0; j < 8; ++j) {
        _Float16 hh = (_Float16)xs[j];
        Bh[c][j] = hh;
        Bl[c][j] = (_Float16)(xs[j] - (float)hh);
      }
    }
  }

  unsigned long long kmin = ~0ull;
#pragma unroll
  for (int ut = 0; ut < 2; ++ut) {
    const int u0 = h * 512 + wv * 32 + ut * 16;
    half8 Ah[4], Al[4];
    float w2p = 0.f;
    {
      const float* wr = w + (u0 + r) * DIM + q * 8;
#pragma unroll
      for (int c = 0; c < 4; ++c) {
        float4 v0 = *reinterpret_cast<const float4*>(wr + c * 32);
        float4 v1 = *reinterpret_cast<const float4*>(wr + c * 32 + 4);
        float wsb[8] = {v0.x, v0.y, v0.z, v0.w, v1.x, v1.y, v1.z, v1.w};
#pragma unroll
        for (int j = 0; j < 8; ++j) {
          float vv = wsb[j];
          w2p = fmaf(vv, vv, w2p);
          _Float16 hh = (_Float16)vv;
          Ah[c][j] = hh;
          Al[c][j] = (_Float16)(vv - (float)hh);
        }
      }
    }
    w2p += __shfl_xor(w2p, 16);
    w2p += __shfl_xor(w2p, 32);

    floatx4 acc = {0.f, 0.f, 0.f, 0.f};
#pragma unroll
    for (int c = 0; c < 4; ++c) {
      acc = __builtin_amdgcn_mfma_f32_16x16x32_f16(Ah[c], Bh[c], acc, 0, 0, 0);
      acc = __builtin_amdgcn_mfma_f32_16x16x32_f16(Ah[c], Bl[c], acc, 0, 0, 0);
      acc = __builtin_amdgcn_mfma_f32_16x16x32_f16(Al[c], Bh[c], acc, 0, 0, 0);
    }
#pragma unroll
    for (int i = 0; i < 4; ++i) {
      float w2v = __shfl(w2p, q * 4 + i);
      float s = w2v - 2.0f * acc[i];
      unsigned int sb = __float_as_uint(s);
      sb ^= (sb >> 31) ? 0xFFFFFFFFu : 0x80000000u;   // total order
      unsigned long long key =
          ((unsigned long long)sb << 32) | (unsigned int)(u0 + q * 4 + i);
      if (key < kmin) kmin = key;
    }
  }
  // reduce over quads (units), then across waves
  unsigned long long o;
  o = __shfl_xor(kmin, 16); if (o < kmin) kmin = o;
  o = __shfl_xor(kmin, 32); if (o < kmin) kmin = o;
  if (lane < 16) kb[wv][r] = kmin;
  __syncthreads();

  unsigned long long m = ~0ull;
  if (t < 16) {
    m = kb[0][t];
#pragma unroll
    for (int k = 1; k < 16; ++k)
      if (kb[k][t] < m) m = kb[k][t];
    __hip_atomic_store(&keys[h * BATCH + b0 + t], m,
                       __ATOMIC_RELAXED, __HIP_MEMORY_SCOPE_AGENT);
  }
  __syncthreads();   // emits s_waitcnt vmcnt(0): key stores drained pre-flag

  if (t == 0) {
    oldflag = (int)__hip_atomic_fetch_add(&flags[bg], 1u,
                  __ATOMIC_ACQ_REL, __HIP_MEMORY_SCOPE_AGENT);
  }
  __syncthreads();
  if (oldflag == 0) return;            // first arriver of the pair exits

  // second arriver: combine halves, bin 16 batches into global S/cnt
  if (t < 16) {
    unsigned long long pk = __hip_atomic_load(&keys[(h ^ 1) * BATCH + b0 + t],
                               __ATOMIC_RELAXED, __HIP_MEMORY_SCOPE_AGENT);
    if (pk < m) m = pk;
    vcell[t] = (unsigned int)m;        // unit id lives in low 32 bits
  }
  __syncthreads();

  const int bi = t >> 6;               // batch within group (16)
  const int d0 = (t & 63) * 2;         // 2 dims per lane
  const unsigned int v = vcell[bi];
  float2 xv = *reinterpret_cast<const float2*>(&x[(b0 + bi) * DIM + d0]);
  atomicAdd(&S[d0 * MN + v], xv.x);
  atomicAdd(&S[(d0 + 1) * MN + v], xv.y);
  if ((t & 63) == 0) atomicAdd(&cnt[v], 1.0f);
}

// ---------------------------------------------------------------------------
// Kernel 2: pure separable conv + finalize. 256 blocks x 512.
// Block = (channel quad q = bid>>3, ux-group uxg = bid&7).
// Stage 1 is now a coalesced 20 KB load of the pre-binned S/cnt slices into
// the skewed LDS layout (plane stride 1064, row stride 33 => <=2-way LDS
// aliasing, free). No key reads, no x gather, no LDS atomics, no bin zeroing.
// ---------------------------------------------------------------------------
#define PLANE 1064
__global__ __launch_bounds__(512) void conv_kernel(
    const float* __restrict__ ws, const float* __restrict__ w,
    const int* __restrict__ itp, float* __restrict__ out)
{
  __shared__ float bin[4 * PLANE + 32 * 33];   // 4 S-planes + cnt plane
  __shared__ float gxt[64], gyt[64];
  __shared__ float T1[4][32][4];
  __shared__ float Tcc[4][32];

  const int t   = threadIdx.x;
  const int q   = blockIdx.x >> 3;
  const int uxg = blockIdx.x & 7;

  const float* Sq  = ws + S_OFF + (q * 4) * MN;
  const float* cnt = ws + CNT_OFF;

  // load 4 channel planes + cnt plane into skewed LDS (coalesced reads)
#pragma unroll
  for (int i = t; i < 4096; i += 512) {
    int j = i >> 10, v = i & 1023;
    bin[j * PLANE + (v >> 5) * 33 + (v & 31)] = Sq[j * MN + v];
  }
#pragma unroll
  for (int i = t; i < 1024; i += 512) {
    bin[4 * PLANE + (i >> 5) * 33 + (i & 31)] = cnt[i];
  }

  const float lr_decay = 1.0f - (float)itp[0] * 0.01f;
  const float alpha_op = ALPHA * lr_decay;
  const float sg       = SIGMA * lr_decay;
  const float c2       = -LOG2E / (sg * sg);
  if (t < 63) {
    float dd = (float)(t - 31);
    float g = __builtin_amdgcn_exp2f(c2 * dd * dd);
    gxt[t] = g;
    gyt[t] = alpha_op * g;             // fold alpha into pass 2
  }
  __syncthreads();

  const int ui  = t >> 7;              // 0..3 -> ux = uxg*4+ui
  const int ux  = uxg * 4 + ui;
  const int rem = t & 127;
  const int vy  = rem >> 2;            // also uy in pass 2
  const int j   = rem & 3;

  // pass 1 (over vx)
  {
    float a = 0.f, ac = 0.f;
    const float* Sp = bin + j * PLANE + vy * 33;
    const float* Cp = bin + 4 * PLANE + vy * 33;
#pragma unroll 8
    for (int vx = 0; vx < 32; ++vx) {
      float g = gxt[ux - vx + 31];
      a = fmaf(g, Sp[vx], a);
      if (j == 0) ac = fmaf(g, Cp[vx], ac);
    }
    T1[ui][vy][j] = a;
    if (j == 0) Tcc[ui][vy] = ac;
  }
  __syncthreads();

  // pass 2 (over vy) + finalize
  {
    const int uy = vy;
    float d = 0.f, rs = 0.f;
#pragma unroll 8
    for (int v = 0; v < 32; ++v) {
      float g = gyt[uy - v + 31];
      d  = fmaf(g, T1[ui][v][j], d);
      rs = fmaf(g, Tcc[ui][v], rs);
    }
    int p = (uy * 32 + ux) * DIM + q * 4 + j;
    out[p] = w[p] * (1.0f - rs) + d;
  }
}

extern "C" void kernel_launch(void* const* d_in, const int* in_sizes, int n_in,
                              void* d_out, int out_size, void* d_ws, size_t ws_size,
                              hipStream_t stream) {
  const float* x   = (const float*)d_in[0];   // [2048,128] f32
  const float* w   = (const float*)d_in[1];   // [1024,128] f32
  const int*   itp = (const int*)d_in[3];     // [1] i32
  float* out = (float*)d_out;                 // [1024,128] f32
  float* ws  = (float*)d_ws;

  // zero S + cnt + flags (529 KB); keys need no init (fully written each run)
  hipMemsetAsync(d_ws, 0, MEMSET_BYTES, stream);
  bmu_bin_kernel<<<256, 1024, 0, stream>>>(x, w, ws);
  conv_kernel<<<256, 512, 0, stream>>>(ws, w, itp, out);
}

// Round 2
// 88.035 us; speedup vs baseline: 1.0905x; 1.0905x over previous
//
#include <hip/hip_runtime.h>
#include <stdint.h>

#define DIM   128
#define MN    1024
#define BATCH 2048
#define ALPHA 0.3f
#define SIGMA 16.0f
#define LOG2E 1.44269504088896f

typedef _Float16 half8 __attribute__((ext_vector_type(8)));
typedef float    floatx4 __attribute__((ext_vector_type(4)));

// ws byte offsets (all regions fully rewritten every iteration -> poison-safe,
// no memset node needed):
//   W  @ 0        : 64 unit-tiles * 8192 B   (per (tile,c): hi 1 KB + lo 1 KB)
//   X  @ 512 KB   : 128 batch-tiles * 8192 B (same layout)
//   XQ @ 1536 KB  : quad-major f32 transpose of x: [32][2048] float4 (1 MB)
//   W2 @ 2560 KB  : 1024 f32 (|w|^2, bit-exact same reduce order as before)
//   K  @ 2564 KB  : keys u64 [4][2048] (64 KB)
#define W_OFF   0
#define X_OFF   (512 * 1024)
#define XQ_OFF  (1536 * 1024)
#define W2_OFF  (2560 * 1024)
#define KEY_OFF (2564 * 1024)

// ---------------------------------------------------------------------------
// Kernel 0: prep. 36 blocks x 1024 thr (~0.3 us).
// Converts w and x f32 -> hi/lo f16 ONCE (was recomputed in every BMU block),
// stored in the exact per-lane MFMA fragment order so the BMU kernel loads
// fragments with plain dwordx4. Math is element-wise identical to the old
// in-register split (cvt RN, sub, cvt), and w2 uses the identical per-lane
// c/j accumulation + shfl_xor 16/32 order => BMU argmin is bit-identical.
// Also writes XQ (quad-major x copy) so the conv kernel's gather coalesces.
// ---------------------------------------------------------------------------
__global__ __launch_bounds__(1024) void prep_kernel(
    const float* __restrict__ x, const float* __restrict__ w,
    uint8_t* __restrict__ ws)
{
  const int t    = threadIdx.x;
  const int lane = t & 63;
  const int wv   = t >> 6;
  const int r    = lane & 15;
  const int q    = lane >> 4;
  const int bid  = blockIdx.x;

  if (bid < 4) {
    // w: wave per unit-tile (16 units x 128 dims), full c-loop (w2 exactness)
    const int tu = bid * 16 + wv;                    // 0..63
    const float* wr = w + (tu * 16 + r) * DIM + q * 8;
    uint8_t* Wc = ws + W_OFF + tu * 8192;
    float w2p = 0.f;
#pragma unroll
    for (int c = 0; c < 4; ++c) {
      float4 v0 = *reinterpret_cast<const float4*>(wr + c * 32);
      float4 v1 = *reinterpret_cast<const float4*>(wr + c * 32 + 4);
      float s[8] = {v0.x, v0.y, v0.z, v0.w, v1.x, v1.y, v1.z, v1.w};
      half8 hh, ll;
#pragma unroll
      for (int j = 0; j < 8; ++j) {
        float vv = s[j];
        w2p = fmaf(vv, vv, w2p);
        _Float16 h = (_Float16)vv;
        hh[j] = h;
        ll[j] = (_Float16)(vv - (float)h);
      }
      *reinterpret_cast<half8*>(Wc + c * 2048 + lane * 16) = hh;
      *reinterpret_cast<half8*>(Wc + c * 2048 + 1024 + lane * 16) = ll;
    }
    w2p += __shfl_xor(w2p, 16);
    w2p += __shfl_xor(w2p, 32);
    if (q == 0)
      reinterpret_cast<float*>(ws + W2_OFF)[tu * 16 + r] = w2p;
  } else {
    // x: wave per (batch-tile, c) quarter; also quad-major transpose store
    const int g  = (bid - 4) * 16 + wv;              // 0..511
    const int tb = g >> 2, c = g & 3;
    const int b  = tb * 16 + r;
    const float* xr = x + b * DIM + q * 8 + c * 32;
    float4 v0 = *reinterpret_cast<const float4*>(xr);
    float4 v1 = *reinterpret_cast<const float4*>(xr + 4);
    float s[8] = {v0.x, v0.y, v0.z, v0.w, v1.x, v1.y, v1.z, v1.w};
    half8 hh, ll;
#pragma unroll
    for (int j = 0; j < 8; ++j) {
      float vv = s[j];
      _Float16 h = (_Float16)vv;
      hh[j] = h;
      ll[j] = (_Float16)(vv - (float)h);
    }
    uint8_t* Xc = ws + X_OFF + tb * 8192 + c * 2048;
    *reinterpret_cast<half8*>(Xc + lane * 16) = hh;
    *reinterpret_cast<half8*>(Xc + 1024 + lane * 16) = ll;
    float4* XQ = reinterpret_cast<float4*>(ws + XQ_OFF);
    XQ[(2 * q + 8 * c) * BATCH + b]     = v0;   // dims qq*4..+3
    XQ[(2 * q + 8 * c + 1) * BATCH + b] = v1;   // dims (qq+1)*4..+3
  }
}

// ---------------------------------------------------------------------------
// Kernel 1: BMU (slim). 256 blocks x 1024 thr (16 waves).
// Block = (bgrp = bid>>2 : 32 batches, qd = bid&3 : 256 units). Wave wv owns
// unit-tile tu = qd*16+wv and both batch-tiles. Pure load->MFMA->argmin:
// per-lane VALU ~120 instrs (was ~500 with in-register conversion); w bytes
// re-read per unit halved (32 MB aggregate, L2-resident). MFMA inputs and
// accumulation order are bit-identical to the previous kernel, so the argmin
// (and first-index tie-break via unit-id low bits) is unchanged.
// keys[qd][b] plain u64 stores; conv min-combines the 4 quarters.
// ---------------------------------------------------------------------------
__global__ __launch_bounds__(1024) void bmu_kernel(uint8_t* __restrict__ ws)
{
  __shared__ unsigned long long kb[16][2][16];

  const int t    = threadIdx.x;
  const int lane = t & 63;
  const int wv   = t >> 6;
  const int r    = lane & 15;
  const int q    = lane >> 4;
  const int bgrp = blockIdx.x >> 2;    // 0..63 -> batches bgrp*32..+31
  const int qd   = blockIdx.x & 3;     // unit quarter
  const int tu   = qd * 16 + wv;
  const int u0   = tu * 16;

  const uint8_t* Wc = ws + W_OFF + tu * 8192;
  half8 Ah[4], Al[4];
#pragma unroll
  for (int c = 0; c < 4; ++c) {
    Ah[c] = *reinterpret_cast<const half8*>(Wc + c * 2048 + lane * 16);
    Al[c] = *reinterpret_cast<const half8*>(Wc + c * 2048 + 1024 + lane * 16);
  }
  const float w2row = reinterpret_cast<const float*>(ws + W2_OFF)[u0 + r];

  unsigned long long kmin[2] = {~0ull, ~0ull};
#pragma unroll
  for (int bt = 0; bt < 2; ++bt) {
    const uint8_t* Xc = ws + X_OFF + (bgrp * 2 + bt) * 8192;
    floatx4 acc = {0.f, 0.f, 0.f, 0.f};
#pragma unroll
    for (int c = 0; c < 4; ++c) {
      half8 Bh = *reinterpret_cast<const half8*>(Xc + c * 2048 + lane * 16);
      half8 Bl = *reinterpret_cast<const half8*>(Xc + c * 2048 + 1024 + lane * 16);
      acc = __builtin_amdgcn_mfma_f32_16x16x32_f16(Ah[c], Bh, acc, 0, 0, 0);
      acc = __builtin_amdgcn_mfma_f32_16x16x32_f16(Ah[c], Bl, acc, 0, 0, 0);
      acc = __builtin_amdgcn_mfma_f32_16x16x32_f16(Al[c], Bh, acc, 0, 0, 0);
    }
#pragma unroll
    for (int i = 0; i < 4; ++i) {
      float w2v = __shfl(w2row, q * 4 + i);
      float s = w2v - 2.0f * acc[i];
      unsigned int sb = __float_as_uint(s);
      sb ^= (sb >> 31) ? 0xFFFFFFFFu : 0x80000000u;   // total order
      unsigned long long key =
          ((unsigned long long)sb << 32) | (unsigned int)(u0 + q * 4 + i);
      if (key < kmin[bt]) kmin[bt] = key;
    }
  }
#pragma unroll
  for (int bt = 0; bt < 2; ++bt) {
    unsigned long long km = kmin[bt], o;
    o = __shfl_xor(km, 16); if (o < km) km = o;
    o = __shfl_xor(km, 32); if (o < km) km = o;
    if (lane < 16) kb[wv][bt][r] = km;
  }
  __syncthreads();
  if (t < 32) {
    unsigned long long m = kb[0][t >> 4][t & 15];
#pragma unroll
    for (int k = 1; k < 16; ++k) {
      unsigned long long v = kb[k][t >> 4][t & 15];
      if (v < m) m = v;
    }
    unsigned long long* keys =
        reinterpret_cast<unsigned long long*>(ws + KEY_OFF);
    keys[qd * BATCH + bgrp * 32 + t] = m;   // batch = bgrp*32 + bt*16 + r = +t
  }
}

// ---------------------------------------------------------------------------
// Kernel 2: LDS-binned gather + separable conv + finalize. 256 blocks x 1024.
// Block = (channel quad q = bid>>3, ux-group uxg = bid&7). Binning is back in
// LDS (skewed layout, <=2-way aliasing) — the round-1 global-atomic variant
// cost several us. New: 2 batches/thread (more TLP) and the gather reads the
// quad-major XQ copy -> fully coalesced float4 stream instead of 512B-stride
// scatter. Conv passes unchanged on t<512.
// ---------------------------------------------------------------------------
#define PLANE 1064                    // 32*33 + 8: bank-skew between j-planes
__global__ __launch_bounds__(1024) void conv_kernel(
    const uint8_t* __restrict__ ws, const float* __restrict__ w,
    const int* __restrict__ itp, float* __restrict__ out)
{
  __shared__ float bin[4 * PLANE + 32 * 33];   // 4 S-planes + cnt plane
  __shared__ float gxt[64], gyt[64];
  __shared__ float T1[4][32][4];
  __shared__ float Tcc[4][32];

  const int t   = threadIdx.x;
  const int q   = blockIdx.x >> 3;
  const int uxg = blockIdx.x & 7;

  for (int i = t; i < 4 * PLANE + 32 * 33; i += 1024) bin[i] = 0.f;

  const float lr_decay = 1.0f - (float)itp[0] * 0.01f;
  const float alpha_op = ALPHA * lr_decay;
  const float sg       = SIGMA * lr_decay;
  const float c2       = -LOG2E / (sg * sg);
  if (t < 63) {
    float dd = (float)(t - 31);
    float g = __builtin_amdgcn_exp2f(c2 * dd * dd);
    gxt[t] = g;
    gyt[t] = alpha_op * g;             // fold alpha into pass 2
  }
  __syncthreads();

  const unsigned long long* keys =
      reinterpret_cast<const unsigned long long*>(ws + KEY_OFF);
  const float4* XQ =
      reinterpret_cast<const float4*>(ws + XQ_OFF) + q * BATCH;
#pragma unroll
  for (int s = 0; s < 2; ++s) {
    int b = s * 1024 + t;
    unsigned long long k0 = keys[b];
    unsigned long long k1 = keys[BATCH + b];
    unsigned long long k2 = keys[2 * BATCH + b];
    unsigned long long k3 = keys[3 * BATCH + b];
    unsigned long long km = k0 < k1 ? k0 : k1;
    if (k2 < km) km = k2;
    if (k3 < km) km = k3;
    unsigned int v = (unsigned int)km;  // unit id in low bits
    int vy = v >> 5, vx = v & 31;
    float4 xv = XQ[b];                  // coalesced
    int base = vy * 33 + vx;
    atomicAdd(&bin[0 * PLANE + base], xv.x);
    atomicAdd(&bin[1 * PLANE + base], xv.y);
    atomicAdd(&bin[2 * PLANE + base], xv.z);
    atomicAdd(&bin[3 * PLANE + base], xv.w);
    atomicAdd(&bin[4 * PLANE + base], 1.0f);
  }
  __syncthreads();

  if (t < 512) {
    const int ui  = t >> 7;              // 0..3 -> ux = uxg*4+ui
    const int ux  = uxg * 4 + ui;
    const int rem = t & 127;
    const int vy  = rem >> 2;            // also uy in pass 2
    const int j   = rem & 3;
    float a = 0.f, ac = 0.f;
    const float* Sp = bin + j * PLANE + vy * 33;
    const float* Cp = bin + 4 * PLANE + vy * 33;
#pragma unroll 8
    for (int vx = 0; vx < 32; ++vx) {
      float g = gxt[ux - vx + 31];
      a = fmaf(g, Sp[vx], a);
      if (j == 0) ac = fmaf(g, Cp[vx], ac);
    }
    T1[ui][vy][j] = a;
    if (j == 0) Tcc[ui][vy] = ac;
  }
  __syncthreads();

  if (t < 512) {
    const int ui  = t >> 7;
    const int ux  = uxg * 4 + ui;
    const int rem = t & 127;
    const int uy  = rem >> 2;
    const int j   = rem & 3;
    float d = 0.f, rs = 0.f;
#pragma unroll 8
    for (int v = 0; v < 32; ++v) {
      float g = gyt[uy - v + 31];
      d  = fmaf(g, T1[ui][v][j], d);
      rs = fmaf(g, Tcc[ui][v], rs);
    }
    int p = (uy * 32 + ux) * DIM + q * 4 + j;
    out[p] = w[p] * (1.0f - rs) + d;
  }
}

extern "C" void kernel_launch(void* const* d_in, const int* in_sizes, int n_in,
                              void* d_out, int out_size, void* d_ws, size_t ws_size,
                              hipStream_t stream) {
  const float* x   = (const float*)d_in[0];   // [2048,128] f32
  const float* w   = (const float*)d_in[1];   // [1024,128] f32
  const int*   itp = (const int*)d_in[3];     // [1] i32
  float* out = (float*)d_out;                 // [1024,128] f32
  uint8_t* ws = (uint8_t*)d_ws;

  prep_kernel<<<36, 1024, 0, stream>>>(x, w, ws);
  bmu_kernel<<<256, 1024, 0, stream>>>(ws);
  conv_kernel<<<256, 1024, 0, stream>>>(ws, w, itp, out);
}